// Round 11
// baseline (1027.197 us; speedup 1.0000x reference)
//
#include <hip/hip_runtime.h>
#include <math.h>

// ---------------- problem constants ----------------
#define BB_   32
#define NN_   577
#define CC_   768
#define HH_   12
#define HD_   64
#define NPAD  640          // padded token dim (10 tiles of 64)
#define BH_   (BB_*HH_)    // 384
#define MQ    (BB_*NN_)    // 18464 rows of x
#define KEPT  462
#define KEPTP 464
#define MP    (BB_*KEPT)   // 14784
#define TOPK  461

#define MT_   145          // qkv m-tiles (128 rows)
#define NT_   18           // qkv n-tiles (128 cols)

using short8 = __attribute__((ext_vector_type(8))) short;
using f32x4  = __attribute__((ext_vector_type(4))) float;
using u16x4  = __attribute__((ext_vector_type(4))) unsigned short;
using u32x2  = __attribute__((ext_vector_type(2))) unsigned int;

using gp1_t = const __attribute__((address_space(1))) void*;
using sp3_t = __attribute__((address_space(3))) void*;

__device__ __forceinline__ unsigned short f2bf(float f) {
  unsigned int u = __float_as_uint(f);
  u += 0x7fffu + ((u >> 16) & 1u);
  return (unsigned short)(u >> 16);
}
__device__ __forceinline__ float bf2f(unsigned short h) {
  return __uint_as_float(((unsigned int)h) << 16);
}
__device__ __forceinline__ f32x4 mfma16(short8 a, short8 b, f32x4 c) {
  return __builtin_amdgcn_mfma_f32_16x16x32_bf16(a, b, c, 0, 0, 0);
}
__device__ __forceinline__ void gl_lds16(const void* g, void* l) {
  __builtin_amdgcn_global_load_lds((gp1_t)g, (sp3_t)l, 16, 0, 0);
}

#define SC_ 0.18033688011112042f   /* 0.125 * log2(e): exp2-domain logits */

// ---------------- K0: fused fp32 -> bf16 hi/lo splits (x, qkv_w, proj_w) ----
__device__ __forceinline__ void split4(const float* __restrict__ in, int i,
                                       unsigned short* __restrict__ hi,
                                       unsigned short* __restrict__ lo) {
  f32x4 f = *(const f32x4*)(in + (size_t)i * 4);
  u16x4 hv, lv;
#pragma unroll
  for (int j = 0; j < 4; ++j) {
    unsigned short h = f2bf(f[j]);
    hv[j] = h;
    lv[j] = f2bf(f[j] - bf2f(h));
  }
  *(u16x4*)(hi + (size_t)i * 4) = hv;
  if (lo) *(u16x4*)(lo + (size_t)i * 4) = lv;
}

#define NX4_ (MQ * 768 / 4)
#define NW4_ (2304 * 768 / 4)
#define NP4_ (768 * 768 / 4)

// all three 4-chunk counts are even, so a (2i, 2i+1) pair never straddles
__global__ __launch_bounds__(256) void k_split_all(
    const float* __restrict__ x, const float* __restrict__ qw,
    const float* __restrict__ pw,
    unsigned short* __restrict__ xh, unsigned short* __restrict__ xl,
    unsigned short* __restrict__ wh, unsigned short* __restrict__ wl,
    unsigned short* __restrict__ pwh) {
  int i2 = blockIdx.x * 256 + threadIdx.x;
#pragma unroll
  for (int s = 0; s < 2; ++s) {
    int i = 2 * i2 + s;
    if (i < NX4_) {
      split4(x, i, xh, xl);
    } else if (i < NX4_ + NW4_) {
      split4(qw, i - NX4_, wh, wl);
    } else if (i < NX4_ + NW4_ + NP4_) {
      split4(pw, i - NX4_ - NW4_, pwh, (unsigned short*)nullptr);
    }
  }
}

// ---------------- K1: QKV GEMM 128x128 tile, B direct-from-L2 ---------------
// A (57MB x-panel, HBM-heavy) staged via global_load_lds as before; B (7MB
// weights, L2/L3-resident) read directly into registers. LDS 64->34KB ->
// 4 blocks/CU: doubles cross-block TLP covering each block's barrier drain.
__global__ __launch_bounds__(256, 4) void k_qkv(
    const unsigned short* __restrict__ xh, const unsigned short* __restrict__ xl,
    const unsigned short* __restrict__ wh, const unsigned short* __restrict__ wl,
    unsigned short* __restrict__ qh, unsigned short* __restrict__ ql,
    unsigned short* __restrict__ kh, unsigned short* __restrict__ kl,
    unsigned short* __restrict__ vt) {
  __shared__ char smem[34816];   // staging: Ah[16K] | Al[16K]; epilogue: lC 33792B
  unsigned short* lAh = (unsigned short*)smem;
  unsigned short* lAl = (unsigned short*)(smem + 16384);

  const int tid = threadIdx.x;
  const int wave = tid >> 6, lane = tid & 63, lr = lane & 15, lg = lane >> 4;
  const int wm = wave >> 1, wn = wave & 1;

  const int nwg = MT_ * NT_;            // 2610
  const int qq = nwg >> 3, rr = nwg & 7; // 326, 2
  int orig = blockIdx.x;
  int xcd = orig & 7, pos = orig >> 3;
  int wgid = (xcd < rr ? xcd * (qq + 1) : rr * (qq + 1) + (xcd - rr) * qq) + pos;
  const int mt = wgid / NT_, nt = wgid - mt * NT_;
  const int m0 = mt * 128, n0 = nt * 128;
  const int which = n0 / 768;            // 0=q 1=k 2=v
  const bool three = (which < 2);

  // per-lane B row bases (rows are fixed across K-steps)
  const unsigned short* wbase[4];
#pragma unroll
  for (int ns = 0; ns < 4; ++ns)
    wbase[ns] = wh + (size_t)(n0 + wn * 64 + ns * 16 + lr) * 768 + lg * 8;
  const ptrdiff_t wlo_d = wl - wh;

  f32x4 zf = {0.f, 0.f, 0.f, 0.f};
  f32x4 acc[4][4];
#pragma unroll
  for (int a = 0; a < 4; ++a)
#pragma unroll
    for (int bq = 0; bq < 4; ++bq) acc[a][bq] = zf;

  for (int ks = 0; ks < 12; ++ks) {
    const int k0 = ks * 64;
    // stage A only: 128x64 hi (+lo), 4 chunks/thread each
#pragma unroll
    for (int it = 0; it < 4; ++it) {
      int c = it * 256 + tid;
      int row = c >> 3, slot = c & 7;
      int grow = m0 + row; if (grow > MQ - 1) grow = MQ - 1;
      int gk = k0 + ((slot ^ (row & 7)) << 3);
      gl_lds16(xh + (size_t)grow * 768 + gk,
               (char*)lAh + (it * 256 + wave * 64) * 16);
      if (three)
        gl_lds16(xl + (size_t)grow * 768 + gk,
                 (char*)lAl + (it * 256 + wave * 64) * 16);
    }
    __syncthreads();

#pragma unroll
    for (int kk = 0; kk < 2; ++kk) {
      // B fragments straight from global (L2-hot weights)
      short8 fb[4], fbl[4];
#pragma unroll
      for (int ns = 0; ns < 4; ++ns) {
        const unsigned short* p = wbase[ns] + k0 + kk * 32;
        fb[ns] = *(const short8*)p;
        if (three) fbl[ns] = *(const short8*)(p + wlo_d);
      }
      short8 fa[4], fal[4];
#pragma unroll
      for (int ms = 0; ms < 4; ++ms) {
        int row = wm * 64 + ms * 16 + lr;
        int off = (kk * 64 + lg * 16) ^ ((row & 7) << 4);
        fa[ms] = *(const short8*)((const char*)lAh + row * 128 + off);
        if (three) fal[ms] = *(const short8*)((const char*)lAl + row * 128 + off);
      }
#pragma unroll
      for (int ms = 0; ms < 4; ++ms)
#pragma unroll
        for (int ns = 0; ns < 4; ++ns) {
          acc[ms][ns] = mfma16(fa[ms], fb[ns], acc[ms][ns]);
          if (three) {
            acc[ms][ns] = mfma16(fa[ms], fbl[ns], acc[ms][ns]);
            acc[ms][ns] = mfma16(fal[ms], fb[ns], acc[ms][ns]);
          }
        }
    }
    __syncthreads();
  }

  if (which < 2) {
    float* lC = (float*)smem;  // [128][66] = 33792 B
    for (int p = 0; p < 2; ++p) {
      if (p) __syncthreads();
      if (wn == p) {
#pragma unroll
        for (int ms = 0; ms < 4; ++ms)
#pragma unroll
          for (int ns = 0; ns < 4; ++ns) {
            int r = wm * 64 + ms * 16 + 4 * lg;
            int cc = ns * 16 + lr;
#pragma unroll
            for (int reg = 0; reg < 4; ++reg)
              lC[(r + reg) * 66 + cc] = acc[ms][ns][reg];
          }
      }
      __syncthreads();
      const int h = ((n0 % 768) >> 6) + p;
      int r = tid >> 1, c0 = (tid & 1) * 32;
      int m = m0 + r;
      if (m < MQ) {
        int b = m / 577, n = m % 577;
        size_t base = ((size_t)(b * 12 + h) * NPAD + n) * 64 + c0;
        unsigned short* dh = (which == 0 ? qh : kh) + base;
        unsigned short* dl = (which == 0 ? ql : kl) + base;
#pragma unroll
        for (int cc = 0; cc < 32; cc += 4) {
          u16x4 hv, lv;
#pragma unroll
          for (int j = 0; j < 4; ++j) {
            float f = lC[r * 66 + c0 + cc + j];
            unsigned short hh = f2bf(f);
            hv[j] = hh;
            lv[j] = f2bf(f - bf2f(hh));
          }
          *(u16x4*)(dh + cc) = hv;
          *(u16x4*)(dl + cc) = lv;
        }
      }
    }
  } else {
    // V: direct fragment stores to transposed layout (B,H,64,NPAD)
    const int h0 = (n0 % 768) >> 6;
#pragma unroll
    for (int ms = 0; ms < 4; ++ms)
#pragma unroll
      for (int ns = 0; ns < 4; ++ns) {
        int m = m0 + wm * 64 + ms * 16 + 4 * lg;
        int c = wn * 64 + ns * 16 + lr;
        int h = h0 + (c >> 6), d = c & 63;
        int b = m / 577, n = m - b * 577;
        if (m + 3 < MQ && n + 3 < 577) {
          u16x4 pv;
#pragma unroll
          for (int reg = 0; reg < 4; ++reg) pv[reg] = f2bf(acc[ms][ns][reg]);
          *(u16x4*)(vt + ((size_t)(b * 12 + h) * 64 + d) * NPAD + n) = pv;
        } else {
#pragma unroll
          for (int reg = 0; reg < 4; ++reg) {
            int mm = m + reg;
            if (mm < MQ) {
              int bb = mm / 577, nn = mm - bb * 577;
              vt[((size_t)(bb * 12 + h) * 64 + d) * NPAD + nn] = f2bf(acc[ms][ns][reg]);
            }
          }
        }
      }
  }
}

// ---------------- K2: fused 3-term QK^T + rowsum + PV + normalize + diag ----
// linear grid 1920, block 256 (4 waves). Wave w owns i-rows [i0+32w, +32)
// (two 16-row groups); iterates ALL j in 32-wide chunks; K/V staged in dbuf
// LDS (one barrier/chunk); P relayout via wave-private LDS (no barriers).
__global__ __launch_bounds__(256) void k_attn1(
    const unsigned short* __restrict__ qh, const unsigned short* __restrict__ ql,
    const unsigned short* __restrict__ kh, const unsigned short* __restrict__ kl,
    const unsigned short* __restrict__ vt, float* __restrict__ S0,
    float* __restrict__ Dg, unsigned short* __restrict__ Ob) {
  __shared__ char smem[45056];
  char* lK = smem;            // 2 bufs x (hi[32][128B] | lo[32][128B]) = 16384
  char* lV = smem + 16384;    // 2 bufs x V^T[64][64B] = 8192
  char* lP = smem + 24576;    // 4 waves x 2 iu x 2 pb x [16][80B] = 20480

  int wgid = (blockIdx.x & 7) * 240 + (blockIdx.x >> 3);  // 1920 = 8*240
  const int bh = wgid / 5;
  const int i0 = (wgid - bh * 5) * 128;
  const int tid = threadIdx.x, w = tid >> 6, lane = tid & 63;
  const int lr = lane & 15, lg = lane >> 4;
  const size_t qb = (size_t)bh * NPAD * 64;

  // staging geometry
  const int krow = tid >> 3, kslot = tid & 7;   // K: 32 rows x 8 x 16B
  const int vrow = tid >> 2, vslot = tid & 3;   // V: 64 rows x 4 x 16B
  const size_t ksrc = (size_t)krow * 64 + ((kslot ^ (krow & 7)) << 3);
  const size_t vsrc = ((size_t)bh * 64 + vrow) * NPAD + ((vslot ^ (vrow & 3)) << 3);

  // Q fragments (B-operand): row = i0 + 32w + 16*iu + lr, k = kk*32 + lg*8
  short8 qf[2][2], qfl[2][2];
#pragma unroll
  for (int iu = 0; iu < 2; ++iu) {
    const size_t qrow = qb + (size_t)(i0 + w * 32 + iu * 16 + lr) * 64;
#pragma unroll
    for (int kk = 0; kk < 2; ++kk) {
      qf[iu][kk]  = *(const short8*)(qh + qrow + kk * 32 + lg * 8);
      qfl[iu][kk] = *(const short8*)(ql + qrow + kk * 32 + lg * 8);
    }
  }
  f32x4 zf = {0.f, 0.f, 0.f, 0.f};
  f32x4 oacc[2][4];
#pragma unroll
  for (int iu = 0; iu < 2; ++iu)
#pragma unroll
    for (int ds = 0; ds < 4; ++ds) oacc[iu][ds] = zf;
  float s0[2] = {0.0f, 0.0f};

  // prologue: stage chunk 0 into buf 0
  gl_lds16(kh + qb + ksrc, lK + tid * 16);
  gl_lds16(kl + qb + ksrc, lK + 4096 + tid * 16);
  gl_lds16(vt + vsrc, lV + tid * 16);
  __syncthreads();

  int buf = 0, pb = 0;
  char* lPw = lP + w * 5120;
  for (int jp = 0; jp < 19; ++jp) {
    if (jp < 18) {  // issue next-chunk stage; drains at this chunk's barrier
      int jn = (jp + 1) * 32;
      gl_lds16(kh + qb + (size_t)jn * 64 + ksrc, lK + (buf ^ 1) * 8192 + tid * 16);
      gl_lds16(kl + qb + (size_t)jn * 64 + ksrc, lK + (buf ^ 1) * 8192 + 4096 + tid * 16);
      gl_lds16(vt + vsrc + jn, lV + (buf ^ 1) * 4096 + tid * 16);
    }
#pragma unroll
    for (int t = 0; t < 2; ++t) {
      const int jloc = t * 16 + lr;
      short8 kfh[2], kfl2[2];
#pragma unroll
      for (int kk = 0; kk < 2; ++kk) {
        int off = (kk * 64 + lg * 16) ^ ((jloc & 7) << 4);
        kfh[kk]  = *(const short8*)(lK + buf * 8192 + jloc * 128 + off);
        kfl2[kk] = *(const short8*)(lK + buf * 8192 + 4096 + jloc * 128 + off);
      }
      int jbase = jp * 32 + t * 16 + 4 * lg;
#pragma unroll
      for (int iu = 0; iu < 2; ++iu) {
        f32x4 c = zf;
#pragma unroll
        for (int kk = 0; kk < 2; ++kk) {
          c = mfma16(kfh[kk], qfl[iu][kk], c);
          c = mfma16(kfl2[kk], qf[iu][kk], c);
          c = mfma16(kfh[kk], qf[iu][kk], c);
        }
        // c: [col=i=lr][row=j = t*16 + 4lg+reg]
        float p0 = (jbase + 0 < 577) ? exp2f(c[0] * SC_) : 0.0f;
        float p1 = (jbase + 1 < 577) ? exp2f(c[1] * SC_) : 0.0f;
        float p2 = (jbase + 2 < 577) ? exp2f(c[2] * SC_) : 0.0f;
        float p3 = (jbase + 3 < 577) ? exp2f(c[3] * SC_) : 0.0f;
        s0[iu] += (p0 + p1) + (p2 + p3);
        u32x2 wv;
        wv[0] = (unsigned)f2bf(p0) | ((unsigned)f2bf(p1) << 16);
        wv[1] = (unsigned)f2bf(p2) | ((unsigned)f2bf(p3) << 16);
        *(u32x2*)(lPw + iu * 2560 + pb * 1280 + lr * 80 + t * 32 + lg * 8) = wv;
      }
    }
    asm volatile("" ::: "memory");
    // PV: A = P[i=lr][j 0..31], B = V^T[d][j 0..31]
#pragma unroll
    for (int iu = 0; iu < 2; ++iu) {
      short8 pa = *(const short8*)(lPw + iu * 2560 + pb * 1280 + lr * 80 + lg * 16);
#pragma unroll
      for (int ds = 0; ds < 4; ++ds) {
        int r = ds * 16 + lr;
        int off = (lg * 16) ^ ((r & 3) << 4);
        short8 vf = *(const short8*)(lV + buf * 4096 + r * 64 + off);
        oacc[iu][ds] = mfma16(pa, vf, oacc[iu][ds]);
      }
    }
    asm volatile("" ::: "memory");
    pb ^= 1;
    __syncthreads();   // drains staged loads; releases buf for next overwrite
    buf ^= 1;
  }

  // wave-private epilogue: rowsum reduce, normalize, store
#pragma unroll
  for (int iu = 0; iu < 2; ++iu) {
    float s = s0[iu];
    s += __shfl_xor(s, 16);
    s += __shfl_xor(s, 32);          // lane holds S0[i = lr]
    const int iw = i0 + w * 32 + iu * 16;
    if (lg == 0) S0[(size_t)bh * NPAD + iw + lr] = s;
    float rs[4];
#pragma unroll
    for (int reg = 0; reg < 4; ++reg) rs[reg] = 1.0f / __shfl(s, 4 * lg + reg);
#pragma unroll
    for (int ds = 0; ds < 4; ++ds)
#pragma unroll
      for (int reg = 0; reg < 4; ++reg)
        Ob[((size_t)bh * NPAD + iw + 4 * lg + reg) * 64 + ds * 16 + lr] =
            f2bf(oacc[iu][ds][reg] * rs[reg]);
  }

  // exact fp32 diag logits from hi+lo (rows i0..i0+127; L2-hot)
#pragma unroll
  for (int rr = 0; rr < 2; ++rr) {
    const int row = i0 + rr * 64 + (tid >> 2);
    const int c = tid & 3;
    const size_t base = qb + (size_t)row * 64 + c * 16;
    short8 a0 = *(const short8*)(qh + base), a1 = *(const short8*)(qh + base + 8);
    short8 b0 = *(const short8*)(ql + base), b1 = *(const short8*)(ql + base + 8);
    short8 c0 = *(const short8*)(kh + base), c1 = *(const short8*)(kh + base + 8);
    short8 d0 = *(const short8*)(kl + base), d1 = *(const short8*)(kl + base + 8);
    float acc = 0.0f;
#pragma unroll
    for (int j = 0; j < 8; ++j) {
      float qv = bf2f((unsigned short)a0[j]) + bf2f((unsigned short)b0[j]);
      float kv = bf2f((unsigned short)c0[j]) + bf2f((unsigned short)d0[j]);
      acc += qv * kv;
      float qv1 = bf2f((unsigned short)a1[j]) + bf2f((unsigned short)b1[j]);
      float kv1 = bf2f((unsigned short)c1[j]) + bf2f((unsigned short)d1[j]);
      acc += qv1 * kv1;
    }
    acc += __shfl_xor(acc, 1, 4);
    acc += __shfl_xor(acc, 2, 4);
    if (c == 0) Dg[(size_t)bh * NPAD + row] = acc * SC_;
  }
}

// ---------------- K4: head-mean diag + stable top-461 via pairwise rank -----
__global__ __launch_bounds__(576) void k_select(const float* __restrict__ Dg,
                                                const float* __restrict__ S0,
                                                int* __restrict__ idxk) {
  __shared__ float kbuf[576];
  __shared__ int kflag[576];
  int b = blockIdx.x, t = threadIdx.x;
  if (t < 576) {
    float a = 0.0f;
#pragma unroll
    for (int h = 0; h < 12; ++h) {
      size_t o = (size_t)(b * 12 + h) * NPAD + t + 1;
      a += exp2f(Dg[o]) / S0[o];
    }
    kbuf[t] = a;  // ranking is scale-invariant: skip /12
  }
  __syncthreads();
  if (t < 576) {
    float kt = kbuf[t];
    int cnt = 0;
    for (int j = 0; j < 576; ++j) {
      float kj = kbuf[j];
      cnt += (kj > kt || (kj == kt && j < t)) ? 1 : 0;
    }
    kflag[t] = (cnt < TOPK) ? 1 : 0;
  }
  __syncthreads();
  if (t < 576 && kflag[t]) {
    int pos = 1;  // CLS occupies 0
    for (int j = 0; j < t; ++j) pos += kflag[j];
    idxk[b * KEPTP + pos] = t + 1;
  }
  if (t == 0) {
    idxk[b * KEPTP + 0] = 0;
    idxk[b * KEPTP + 462] = 0;
    idxk[b * KEPTP + 463] = 0;
  }
}

// ---------------- K6: proj GEMM 128x128 + bias + residual gather ------------
// A-panel gathered from Ob via idxk (h = ks). linear grid 696, n-fastest.
__global__ __launch_bounds__(256) void k_proj(
    const unsigned short* __restrict__ Ob, const unsigned short* __restrict__ pwh,
    const float* __restrict__ pb, const float* __restrict__ x,
    const int* __restrict__ idxk, float* __restrict__ out) {
  __shared__ char smem[33792];
  unsigned short* lA = (unsigned short*)smem;
  unsigned short* lB = (unsigned short*)(smem + 16384);
  const int tid = threadIdx.x;
  const int wave = tid >> 6, lane = tid & 63, lr = lane & 15, lg = lane >> 4;
  const int wm = wave >> 1, wn = wave & 1;
  int wgid = (blockIdx.x & 7) * 87 + (blockIdx.x >> 3);  // 696 = 8*87
  const int mt = wgid / 6, nt = wgid - mt * 6;
  const int m0 = mt * 128, n0 = nt * 128;

  // per-thread token/batch for the 4 A-chunks (fixed across K-steps)
  int tokr[4], bbr[4], offr8[4];
#pragma unroll
  for (int it = 0; it < 4; ++it) {
    int c = it * 256 + tid;
    int row = c >> 3, slot = c & 7;
    int m = m0 + row; if (m > MP - 1) m = MP - 1;
    int bb = m / 462, tt = m - bb * 462;
    tokr[it] = idxk[bb * KEPTP + tt];
    bbr[it] = bb;
    offr8[it] = (slot ^ (row & 7)) << 3;
  }

  f32x4 zf = {0.f, 0.f, 0.f, 0.f};
  f32x4 acc[4][4];
#pragma unroll
  for (int a = 0; a < 4; ++a)
#pragma unroll
    for (int bq = 0; bq < 4; ++bq) acc[a][bq] = zf;

  for (int ks = 0; ks < 12; ++ks) {
    int k0 = ks * 64;
#pragma unroll
    for (int it = 0; it < 4; ++it) {
      gl_lds16(Ob + ((size_t)(bbr[it] * 12 + ks) * NPAD + tokr[it]) * 64 + offr8[it],
               (char*)lA + (it * 256 + wave * 64) * 16);
    }
#pragma unroll
    for (int it = 0; it < 4; ++it) {
      int c = it * 256 + tid;
      int row = c >> 3, slot = c & 7;
      int gk = k0 + ((slot ^ (row & 7)) << 3);
      gl_lds16(pwh + (size_t)(n0 + row) * 768 + gk,
               (char*)lB + (it * 256 + wave * 64) * 16);
    }
    __syncthreads();
#pragma unroll
    for (int kk = 0; kk < 2; ++kk) {
      short8 fa[4], fb[4];
#pragma unroll
      for (int ms = 0; ms < 4; ++ms) {
        int row = wm * 64 + ms * 16 + lr;
        int off = (kk * 64 + lg * 16) ^ ((row & 7) << 4);
        fa[ms] = *(const short8*)((const char*)lA + row * 128 + off);
      }
#pragma unroll
      for (int ns = 0; ns < 4; ++ns) {
        int row = wn * 64 + ns * 16 + lr;
        int off = (kk * 64 + lg * 16) ^ ((row & 7) << 4);
        fb[ns] = *(const short8*)((const char*)lB + row * 128 + off);
      }
#pragma unroll
      for (int ms = 0; ms < 4; ++ms)
#pragma unroll
        for (int ns = 0; ns < 4; ++ns)
          acc[ms][ns] = mfma16(fa[ms], fb[ns], acc[ms][ns]);
    }
    __syncthreads();
  }

  float* lC = (float*)smem;  // [128][66]
  for (int p = 0; p < 2; ++p) {
    if (p) __syncthreads();
    if (wn == p) {
#pragma unroll
      for (int ms = 0; ms < 4; ++ms)
#pragma unroll
        for (int ns = 0; ns < 4; ++ns) {
          int r = wm * 64 + ms * 16 + 4 * lg;
          int cc = ns * 16 + lr;
#pragma unroll
          for (int reg = 0; reg < 4; ++reg)
            lC[(r + reg) * 66 + cc] = acc[ms][ns][reg];
        }
    }
    __syncthreads();
    int r = tid >> 1, c0 = (tid & 1) * 32;
    int m = m0 + r;
    if (m < MP) {
      int bb = m / 462, tt = m % 462;
      int tok = idxk[bb * KEPTP + tt];
      int col = n0 + p * 64 + c0;
      const float* xs = x + ((size_t)(bb * 577) + tok) * 768 + col;
      float* dst = out + (size_t)m * 768 + col;
#pragma unroll
      for (int cc = 0; cc < 32; cc += 4) {
        f32x4 xv = *(const f32x4*)(xs + cc);
        f32x4 bv = *(const f32x4*)(pb + col + cc);
        f32x4 o;
#pragma unroll
        for (int j = 0; j < 4; ++j)
          o[j] = lC[r * 66 + c0 + cc + j] + bv[j] + xv[j];
        *(f32x4*)(dst + cc) = o;
      }
    }
  }
}

// ---------------- host launch ----------------
extern "C" void kernel_launch(void* const* d_in, const int* in_sizes, int n_in,
                              void* d_out, int out_size, void* d_ws, size_t ws_size,
                              hipStream_t stream) {
  const float* x  = (const float*)d_in[0];
  const float* qw = (const float*)d_in[1];
  const float* pw = (const float*)d_in[2];
  const float* pb = (const float*)d_in[3];
  (void)in_sizes; (void)n_in; (void)out_size; (void)ws_size;

  char* ws = (char*)d_ws;
  size_t off = 0;
  auto alloc = [&](size_t bytes) {
    void* p = ws + off;
    off += (bytes + 255) & ~(size_t)255;
    return p;
  };
  unsigned short* xh  = (unsigned short*)alloc((size_t)MQ * 768 * 2);
  unsigned short* xl  = (unsigned short*)alloc((size_t)MQ * 768 * 2);
  unsigned short* wh  = (unsigned short*)alloc((size_t)2304 * 768 * 2);
  unsigned short* wl  = (unsigned short*)alloc((size_t)2304 * 768 * 2);
  unsigned short* pwh = (unsigned short*)alloc((size_t)768 * 768 * 2);
  unsigned short* qhp = (unsigned short*)alloc((size_t)BH_ * NPAD * 64 * 2);
  unsigned short* qlp = (unsigned short*)alloc((size_t)BH_ * NPAD * 64 * 2);
  unsigned short* khp = (unsigned short*)alloc((size_t)BH_ * NPAD * 64 * 2);
  unsigned short* klp = (unsigned short*)alloc((size_t)BH_ * NPAD * 64 * 2);
  unsigned short* vtp = (unsigned short*)alloc((size_t)BH_ * NPAD * 64 * 2);
  unsigned short* Obf = (unsigned short*)alloc((size_t)BH_ * NPAD * 64 * 2);
  float* S0  = (float*)alloc((size_t)BH_ * NPAD * 4);
  float* Dg  = (float*)alloc((size_t)BH_ * NPAD * 4);
  int*   idxk = (int*)alloc((size_t)BB_ * KEPTP * 4);

  k_split_all<<<dim3(((NX4_ + NW4_ + NP4_) / 2 + 255) / 256), 256, 0, stream>>>(
      x, qw, pw, xh, xl, wh, wl, pwh);
  k_qkv<<<dim3(MT_ * NT_), 256, 0, stream>>>(xh, xl, wh, wl, qhp, qlp, khp, klp, vtp);
  k_attn1<<<dim3(1920), 256, 0, stream>>>(qhp, qlp, khp, klp, vtp, S0, Dg, Obf);
  k_select<<<dim3(32), 576, 0, stream>>>(Dg, S0, idxk);
  k_proj<<<dim3(696), 256, 0, stream>>>(Obf, pwh, pb, x, idxk, (float*)d_out);
}

// Round 12
// 490.611 us; speedup vs baseline: 2.0937x; 2.0937x over previous
//
#include <hip/hip_runtime.h>
#include <math.h>

// ---------------- problem constants ----------------
#define BB_   32
#define NN_   577
#define CC_   768
#define HH_   12
#define HD_   64
#define NPAD  640          // padded token dim (10 tiles of 64)
#define BH_   (BB_*HH_)    // 384
#define MQ    (BB_*NN_)    // 18464 rows of x
#define KEPT  462
#define KEPTP 464
#define MP    (BB_*KEPT)   // 14784
#define TOPK  461

#define MT_   145          // qkv m-tiles (128 rows)
#define NT_   18           // qkv n-tiles (128 cols)

using short8 = __attribute__((ext_vector_type(8))) short;
using f32x4  = __attribute__((ext_vector_type(4))) float;
using u16x4  = __attribute__((ext_vector_type(4))) unsigned short;
using u32x2  = __attribute__((ext_vector_type(2))) unsigned int;

using gp1_t = const __attribute__((address_space(1))) void*;
using sp3_t = __attribute__((address_space(3))) void*;

__device__ __forceinline__ unsigned short f2bf(float f) {
  unsigned int u = __float_as_uint(f);
  u += 0x7fffu + ((u >> 16) & 1u);
  return (unsigned short)(u >> 16);
}
__device__ __forceinline__ float bf2f(unsigned short h) {
  return __uint_as_float(((unsigned int)h) << 16);
}
__device__ __forceinline__ f32x4 mfma16(short8 a, short8 b, f32x4 c) {
  return __builtin_amdgcn_mfma_f32_16x16x32_bf16(a, b, c, 0, 0, 0);
}
__device__ __forceinline__ void gl_lds16(const void* g, void* l) {
  __builtin_amdgcn_global_load_lds((gp1_t)g, (sp3_t)l, 16, 0, 0);
}

#define SC_ 0.18033688011112042f   /* 0.125 * log2(e): exp2-domain logits */

// ---------------- K0: fused fp32 -> bf16 hi/lo splits (x, qkv_w, proj_w) ----
__device__ __forceinline__ void split4(const float* __restrict__ in, int i,
                                       unsigned short* __restrict__ hi,
                                       unsigned short* __restrict__ lo) {
  f32x4 f = *(const f32x4*)(in + (size_t)i * 4);
  u16x4 hv, lv;
#pragma unroll
  for (int j = 0; j < 4; ++j) {
    unsigned short h = f2bf(f[j]);
    hv[j] = h;
    lv[j] = f2bf(f[j] - bf2f(h));
  }
  *(u16x4*)(hi + (size_t)i * 4) = hv;
  if (lo) *(u16x4*)(lo + (size_t)i * 4) = lv;
}

#define NX4_ (MQ * 768 / 4)
#define NW4_ (2304 * 768 / 4)
#define NP4_ (768 * 768 / 4)

// all three 4-chunk counts are even, so a (2i, 2i+1) pair never straddles
__global__ __launch_bounds__(256) void k_split_all(
    const float* __restrict__ x, const float* __restrict__ qw,
    const float* __restrict__ pw,
    unsigned short* __restrict__ xh, unsigned short* __restrict__ xl,
    unsigned short* __restrict__ wh, unsigned short* __restrict__ wl,
    unsigned short* __restrict__ pwh) {
  int i2 = blockIdx.x * 256 + threadIdx.x;
#pragma unroll
  for (int s = 0; s < 2; ++s) {
    int i = 2 * i2 + s;
    if (i < NX4_) {
      split4(x, i, xh, xl);
    } else if (i < NX4_ + NW4_) {
      split4(qw, i - NX4_, wh, wl);
    } else if (i < NX4_ + NW4_ + NP4_) {
      split4(pw, i - NX4_ - NW4_, pwh, (unsigned short*)nullptr);
    }
  }
}

// ---------------- K1: QKV GEMM 128x128 tile, B direct-from-L2 ---------------
// A (57MB x-panel, HBM-heavy) staged via global_load_lds; B (7MB weights,
// L2/L3-resident) read directly into registers. LDS 64->34KB -> 4 blocks/CU
// via LDS limit (VGPR ~96 allows 5 waves/SIMD). NOTE: min-waves bound must
// stay at 2 — (256,4) clamps VGPR to 64 and spills the accumulator (r11:
// 830us, MfmaUtil 7.5%, 2.2GB scratch traffic per dispatch).
__global__ __launch_bounds__(256, 2) void k_qkv(
    const unsigned short* __restrict__ xh, const unsigned short* __restrict__ xl,
    const unsigned short* __restrict__ wh, const unsigned short* __restrict__ wl,
    unsigned short* __restrict__ qh, unsigned short* __restrict__ ql,
    unsigned short* __restrict__ kh, unsigned short* __restrict__ kl,
    unsigned short* __restrict__ vt) {
  __shared__ char smem[34816];   // staging: Ah[16K] | Al[16K]; epilogue: lC 33792B
  unsigned short* lAh = (unsigned short*)smem;
  unsigned short* lAl = (unsigned short*)(smem + 16384);

  const int tid = threadIdx.x;
  const int wave = tid >> 6, lane = tid & 63, lr = lane & 15, lg = lane >> 4;
  const int wm = wave >> 1, wn = wave & 1;

  const int nwg = MT_ * NT_;            // 2610
  const int qq = nwg >> 3, rr = nwg & 7; // 326, 2
  int orig = blockIdx.x;
  int xcd = orig & 7, pos = orig >> 3;
  int wgid = (xcd < rr ? xcd * (qq + 1) : rr * (qq + 1) + (xcd - rr) * qq) + pos;
  const int mt = wgid / NT_, nt = wgid - mt * NT_;
  const int m0 = mt * 128, n0 = nt * 128;
  const int which = n0 / 768;            // 0=q 1=k 2=v
  const bool three = (which < 2);

  // per-lane B row bases (rows are fixed across K-steps)
  const unsigned short* wbase[4];
#pragma unroll
  for (int ns = 0; ns < 4; ++ns)
    wbase[ns] = wh + (size_t)(n0 + wn * 64 + ns * 16 + lr) * 768 + lg * 8;
  const ptrdiff_t wlo_d = wl - wh;

  f32x4 zf = {0.f, 0.f, 0.f, 0.f};
  f32x4 acc[4][4];
#pragma unroll
  for (int a = 0; a < 4; ++a)
#pragma unroll
    for (int bq = 0; bq < 4; ++bq) acc[a][bq] = zf;

  for (int ks = 0; ks < 12; ++ks) {
    const int k0 = ks * 64;
    // stage A only: 128x64 hi (+lo), 4 chunks/thread each
#pragma unroll
    for (int it = 0; it < 4; ++it) {
      int c = it * 256 + tid;
      int row = c >> 3, slot = c & 7;
      int grow = m0 + row; if (grow > MQ - 1) grow = MQ - 1;
      int gk = k0 + ((slot ^ (row & 7)) << 3);
      gl_lds16(xh + (size_t)grow * 768 + gk,
               (char*)lAh + (it * 256 + wave * 64) * 16);
      if (three)
        gl_lds16(xl + (size_t)grow * 768 + gk,
                 (char*)lAl + (it * 256 + wave * 64) * 16);
    }
    __syncthreads();

#pragma unroll
    for (int kk = 0; kk < 2; ++kk) {
      // B fragments straight from global (L2-hot weights)
      short8 fb[4], fbl[4];
#pragma unroll
      for (int ns = 0; ns < 4; ++ns) {
        const unsigned short* p = wbase[ns] + k0 + kk * 32;
        fb[ns] = *(const short8*)p;
        if (three) fbl[ns] = *(const short8*)(p + wlo_d);
      }
      short8 fa[4], fal[4];
#pragma unroll
      for (int ms = 0; ms < 4; ++ms) {
        int row = wm * 64 + ms * 16 + lr;
        int off = (kk * 64 + lg * 16) ^ ((row & 7) << 4);
        fa[ms] = *(const short8*)((const char*)lAh + row * 128 + off);
        if (three) fal[ms] = *(const short8*)((const char*)lAl + row * 128 + off);
      }
#pragma unroll
      for (int ms = 0; ms < 4; ++ms)
#pragma unroll
        for (int ns = 0; ns < 4; ++ns) {
          acc[ms][ns] = mfma16(fa[ms], fb[ns], acc[ms][ns]);
          if (three) {
            acc[ms][ns] = mfma16(fa[ms], fbl[ns], acc[ms][ns]);
            acc[ms][ns] = mfma16(fal[ms], fb[ns], acc[ms][ns]);
          }
        }
    }
    __syncthreads();
  }

  if (which < 2) {
    float* lC = (float*)smem;  // [128][66] = 33792 B
    for (int p = 0; p < 2; ++p) {
      if (p) __syncthreads();
      if (wn == p) {
#pragma unroll
        for (int ms = 0; ms < 4; ++ms)
#pragma unroll
          for (int ns = 0; ns < 4; ++ns) {
            int r = wm * 64 + ms * 16 + 4 * lg;
            int cc = ns * 16 + lr;
#pragma unroll
            for (int reg = 0; reg < 4; ++reg)
              lC[(r + reg) * 66 + cc] = acc[ms][ns][reg];
          }
      }
      __syncthreads();
      const int h = ((n0 % 768) >> 6) + p;
      int r = tid >> 1, c0 = (tid & 1) * 32;
      int m = m0 + r;
      if (m < MQ) {
        int b = m / 577, n = m % 577;
        size_t base = ((size_t)(b * 12 + h) * NPAD + n) * 64 + c0;
        unsigned short* dh = (which == 0 ? qh : kh) + base;
        unsigned short* dl = (which == 0 ? ql : kl) + base;
#pragma unroll
        for (int cc = 0; cc < 32; cc += 4) {
          u16x4 hv, lv;
#pragma unroll
          for (int j = 0; j < 4; ++j) {
            float f = lC[r * 66 + c0 + cc + j];
            unsigned short hh = f2bf(f);
            hv[j] = hh;
            lv[j] = f2bf(f - bf2f(hh));
          }
          *(u16x4*)(dh + cc) = hv;
          *(u16x4*)(dl + cc) = lv;
        }
      }
    }
  } else {
    // V: direct fragment stores to transposed layout (B,H,64,NPAD)
    const int h0 = (n0 % 768) >> 6;
#pragma unroll
    for (int ms = 0; ms < 4; ++ms)
#pragma unroll
      for (int ns = 0; ns < 4; ++ns) {
        int m = m0 + wm * 64 + ms * 16 + 4 * lg;
        int c = wn * 64 + ns * 16 + lr;
        int h = h0 + (c >> 6), d = c & 63;
        int b = m / 577, n = m - b * 577;
        if (m + 3 < MQ && n + 3 < 577) {
          u16x4 pv;
#pragma unroll
          for (int reg = 0; reg < 4; ++reg) pv[reg] = f2bf(acc[ms][ns][reg]);
          *(u16x4*)(vt + ((size_t)(b * 12 + h) * 64 + d) * NPAD + n) = pv;
        } else {
#pragma unroll
          for (int reg = 0; reg < 4; ++reg) {
            int mm = m + reg;
            if (mm < MQ) {
              int bb = mm / 577, nn = mm - bb * 577;
              vt[((size_t)(bb * 12 + h) * 64 + d) * NPAD + nn] = f2bf(acc[ms][ns][reg]);
            }
          }
        }
      }
  }
}

// ---------------- K2: fused 3-term QK^T + rowsum + PV + normalize + diag ----
// linear grid 1920, block 256 (4 waves). Wave w owns i-rows [i0+32w, +32)
// (two 16-row groups); iterates ALL j in 32-wide chunks; K/V staged in dbuf
// LDS (one barrier/chunk); P relayout via wave-private LDS (no barriers).
__global__ __launch_bounds__(256) void k_attn1(
    const unsigned short* __restrict__ qh, const unsigned short* __restrict__ ql,
    const unsigned short* __restrict__ kh, const unsigned short* __restrict__ kl,
    const unsigned short* __restrict__ vt, float* __restrict__ S0,
    float* __restrict__ Dg, unsigned short* __restrict__ Ob) {
  __shared__ char smem[45056];
  char* lK = smem;            // 2 bufs x (hi[32][128B] | lo[32][128B]) = 16384
  char* lV = smem + 16384;    // 2 bufs x V^T[64][64B] = 8192
  char* lP = smem + 24576;    // 4 waves x 2 iu x 2 pb x [16][80B] = 20480

  int wgid = (blockIdx.x & 7) * 240 + (blockIdx.x >> 3);  // 1920 = 8*240
  const int bh = wgid / 5;
  const int i0 = (wgid - bh * 5) * 128;
  const int tid = threadIdx.x, w = tid >> 6, lane = tid & 63;
  const int lr = lane & 15, lg = lane >> 4;
  const size_t qb = (size_t)bh * NPAD * 64;

  // staging geometry
  const int krow = tid >> 3, kslot = tid & 7;   // K: 32 rows x 8 x 16B
  const int vrow = tid >> 2, vslot = tid & 3;   // V: 64 rows x 4 x 16B
  const size_t ksrc = (size_t)krow * 64 + ((kslot ^ (krow & 7)) << 3);
  const size_t vsrc = ((size_t)bh * 64 + vrow) * NPAD + ((vslot ^ (vrow & 3)) << 3);

  // Q fragments (B-operand): row = i0 + 32w + 16*iu + lr, k = kk*32 + lg*8
  short8 qf[2][2], qfl[2][2];
#pragma unroll
  for (int iu = 0; iu < 2; ++iu) {
    const size_t qrow = qb + (size_t)(i0 + w * 32 + iu * 16 + lr) * 64;
#pragma unroll
    for (int kk = 0; kk < 2; ++kk) {
      qf[iu][kk]  = *(const short8*)(qh + qrow + kk * 32 + lg * 8);
      qfl[iu][kk] = *(const short8*)(ql + qrow + kk * 32 + lg * 8);
    }
  }
  f32x4 zf = {0.f, 0.f, 0.f, 0.f};
  f32x4 oacc[2][4];
#pragma unroll
  for (int iu = 0; iu < 2; ++iu)
#pragma unroll
    for (int ds = 0; ds < 4; ++ds) oacc[iu][ds] = zf;
  float s0[2] = {0.0f, 0.0f};

  // prologue: stage chunk 0 into buf 0
  gl_lds16(kh + qb + ksrc, lK + tid * 16);
  gl_lds16(kl + qb + ksrc, lK + 4096 + tid * 16);
  gl_lds16(vt + vsrc, lV + tid * 16);
  __syncthreads();

  int buf = 0, pb = 0;
  char* lPw = lP + w * 5120;
  for (int jp = 0; jp < 19; ++jp) {
    if (jp < 18) {  // issue next-chunk stage; drains at this chunk's barrier
      int jn = (jp + 1) * 32;
      gl_lds16(kh + qb + (size_t)jn * 64 + ksrc, lK + (buf ^ 1) * 8192 + tid * 16);
      gl_lds16(kl + qb + (size_t)jn * 64 + ksrc, lK + (buf ^ 1) * 8192 + 4096 + tid * 16);
      gl_lds16(vt + vsrc + jn, lV + (buf ^ 1) * 4096 + tid * 16);
    }
#pragma unroll
    for (int t = 0; t < 2; ++t) {
      const int jloc = t * 16 + lr;
      short8 kfh[2], kfl2[2];
#pragma unroll
      for (int kk = 0; kk < 2; ++kk) {
        int off = (kk * 64 + lg * 16) ^ ((jloc & 7) << 4);
        kfh[kk]  = *(const short8*)(lK + buf * 8192 + jloc * 128 + off);
        kfl2[kk] = *(const short8*)(lK + buf * 8192 + 4096 + jloc * 128 + off);
      }
      int jbase = jp * 32 + t * 16 + 4 * lg;
#pragma unroll
      for (int iu = 0; iu < 2; ++iu) {
        f32x4 c = zf;
#pragma unroll
        for (int kk = 0; kk < 2; ++kk) {
          c = mfma16(kfh[kk], qfl[iu][kk], c);
          c = mfma16(kfl2[kk], qf[iu][kk], c);
          c = mfma16(kfh[kk], qf[iu][kk], c);
        }
        // c: [col=i=lr][row=j = t*16 + 4lg+reg]
        float p0 = (jbase + 0 < 577) ? exp2f(c[0] * SC_) : 0.0f;
        float p1 = (jbase + 1 < 577) ? exp2f(c[1] * SC_) : 0.0f;
        float p2 = (jbase + 2 < 577) ? exp2f(c[2] * SC_) : 0.0f;
        float p3 = (jbase + 3 < 577) ? exp2f(c[3] * SC_) : 0.0f;
        s0[iu] += (p0 + p1) + (p2 + p3);
        u32x2 wv;
        wv[0] = (unsigned)f2bf(p0) | ((unsigned)f2bf(p1) << 16);
        wv[1] = (unsigned)f2bf(p2) | ((unsigned)f2bf(p3) << 16);
        *(u32x2*)(lPw + iu * 2560 + pb * 1280 + lr * 80 + t * 32 + lg * 8) = wv;
      }
    }
    asm volatile("" ::: "memory");
    // PV: A = P[i=lr][j 0..31], B = V^T[d][j 0..31]
#pragma unroll
    for (int iu = 0; iu < 2; ++iu) {
      short8 pa = *(const short8*)(lPw + iu * 2560 + pb * 1280 + lr * 80 + lg * 16);
#pragma unroll
      for (int ds = 0; ds < 4; ++ds) {
        int r = ds * 16 + lr;
        int off = (lg * 16) ^ ((r & 3) << 4);
        short8 vf = *(const short8*)(lV + buf * 4096 + r * 64 + off);
        oacc[iu][ds] = mfma16(pa, vf, oacc[iu][ds]);
      }
    }
    asm volatile("" ::: "memory");
    pb ^= 1;
    __syncthreads();   // drains staged loads; releases buf for next overwrite
    buf ^= 1;
  }

  // wave-private epilogue: rowsum reduce, normalize, store
#pragma unroll
  for (int iu = 0; iu < 2; ++iu) {
    float s = s0[iu];
    s += __shfl_xor(s, 16);
    s += __shfl_xor(s, 32);          // lane holds S0[i = lr]
    const int iw = i0 + w * 32 + iu * 16;
    if (lg == 0) S0[(size_t)bh * NPAD + iw + lr] = s;
    float rs[4];
#pragma unroll
    for (int reg = 0; reg < 4; ++reg) rs[reg] = 1.0f / __shfl(s, 4 * lg + reg);
#pragma unroll
    for (int ds = 0; ds < 4; ++ds)
#pragma unroll
      for (int reg = 0; reg < 4; ++reg)
        Ob[((size_t)bh * NPAD + iw + 4 * lg + reg) * 64 + ds * 16 + lr] =
            f2bf(oacc[iu][ds][reg] * rs[reg]);
  }

  // exact fp32 diag logits from hi+lo (rows i0..i0+127; L2-hot)
#pragma unroll
  for (int rr = 0; rr < 2; ++rr) {
    const int row = i0 + rr * 64 + (tid >> 2);
    const int c = tid & 3;
    const size_t base = qb + (size_t)row * 64 + c * 16;
    short8 a0 = *(const short8*)(qh + base), a1 = *(const short8*)(qh + base + 8);
    short8 b0 = *(const short8*)(ql + base), b1 = *(const short8*)(ql + base + 8);
    short8 c0 = *(const short8*)(kh + base), c1 = *(const short8*)(kh + base + 8);
    short8 d0 = *(const short8*)(kl + base), d1 = *(const short8*)(kl + base + 8);
    float acc = 0.0f;
#pragma unroll
    for (int j = 0; j < 8; ++j) {
      float qv = bf2f((unsigned short)a0[j]) + bf2f((unsigned short)b0[j]);
      float kv = bf2f((unsigned short)c0[j]) + bf2f((unsigned short)d0[j]);
      acc += qv * kv;
      float qv1 = bf2f((unsigned short)a1[j]) + bf2f((unsigned short)b1[j]);
      float kv1 = bf2f((unsigned short)c1[j]) + bf2f((unsigned short)d1[j]);
      acc += qv1 * kv1;
    }
    acc += __shfl_xor(acc, 1, 4);
    acc += __shfl_xor(acc, 2, 4);
    if (c == 0) Dg[(size_t)bh * NPAD + row] = acc * SC_;
  }
}

// ---------------- K4: head-mean diag + stable top-461 via pairwise rank -----
__global__ __launch_bounds__(576) void k_select(const float* __restrict__ Dg,
                                                const float* __restrict__ S0,
                                                int* __restrict__ idxk) {
  __shared__ float kbuf[576];
  __shared__ int kflag[576];
  int b = blockIdx.x, t = threadIdx.x;
  if (t < 576) {
    float a = 0.0f;
#pragma unroll
    for (int h = 0; h < 12; ++h) {
      size_t o = (size_t)(b * 12 + h) * NPAD + t + 1;
      a += exp2f(Dg[o]) / S0[o];
    }
    kbuf[t] = a;  // ranking is scale-invariant: skip /12
  }
  __syncthreads();
  if (t < 576) {
    float kt = kbuf[t];
    int cnt = 0;
    for (int j = 0; j < 576; ++j) {
      float kj = kbuf[j];
      cnt += (kj > kt || (kj == kt && j < t)) ? 1 : 0;
    }
    kflag[t] = (cnt < TOPK) ? 1 : 0;
  }
  __syncthreads();
  if (t < 576 && kflag[t]) {
    int pos = 1;  // CLS occupies 0
    for (int j = 0; j < t; ++j) pos += kflag[j];
    idxk[b * KEPTP + pos] = t + 1;
  }
  if (t == 0) {
    idxk[b * KEPTP + 0] = 0;
    idxk[b * KEPTP + 462] = 0;
    idxk[b * KEPTP + 463] = 0;
  }
}

// ---------------- K6: proj GEMM 128x128 + bias + residual gather ------------
// A-panel gathered from Ob via idxk (h = ks). linear grid 696, n-fastest.
__global__ __launch_bounds__(256) void k_proj(
    const unsigned short* __restrict__ Ob, const unsigned short* __restrict__ pwh,
    const float* __restrict__ pb, const float* __restrict__ x,
    const int* __restrict__ idxk, float* __restrict__ out) {
  __shared__ char smem[33792];
  unsigned short* lA = (unsigned short*)smem;
  unsigned short* lB = (unsigned short*)(smem + 16384);
  const int tid = threadIdx.x;
  const int wave = tid >> 6, lane = tid & 63, lr = lane & 15, lg = lane >> 4;
  const int wm = wave >> 1, wn = wave & 1;
  int wgid = (blockIdx.x & 7) * 87 + (blockIdx.x >> 3);  // 696 = 8*87
  const int mt = wgid / 6, nt = wgid - mt * 6;
  const int m0 = mt * 128, n0 = nt * 128;

  // per-thread token/batch for the 4 A-chunks (fixed across K-steps)
  int tokr[4], bbr[4], offr8[4];
#pragma unroll
  for (int it = 0; it < 4; ++it) {
    int c = it * 256 + tid;
    int row = c >> 3, slot = c & 7;
    int m = m0 + row; if (m > MP - 1) m = MP - 1;
    int bb = m / 462, tt = m - bb * 462;
    tokr[it] = idxk[bb * KEPTP + tt];
    bbr[it] = bb;
    offr8[it] = (slot ^ (row & 7)) << 3;
  }

  f32x4 zf = {0.f, 0.f, 0.f, 0.f};
  f32x4 acc[4][4];
#pragma unroll
  for (int a = 0; a < 4; ++a)
#pragma unroll
    for (int bq = 0; bq < 4; ++bq) acc[a][bq] = zf;

  for (int ks = 0; ks < 12; ++ks) {
    int k0 = ks * 64;
#pragma unroll
    for (int it = 0; it < 4; ++it) {
      gl_lds16(Ob + ((size_t)(bbr[it] * 12 + ks) * NPAD + tokr[it]) * 64 + offr8[it],
               (char*)lA + (it * 256 + wave * 64) * 16);
    }
#pragma unroll
    for (int it = 0; it < 4; ++it) {
      int c = it * 256 + tid;
      int row = c >> 3, slot = c & 7;
      int gk = k0 + ((slot ^ (row & 7)) << 3);
      gl_lds16(pwh + (size_t)(n0 + row) * 768 + gk,
               (char*)lB + (it * 256 + wave * 64) * 16);
    }
    __syncthreads();
#pragma unroll
    for (int kk = 0; kk < 2; ++kk) {
      short8 fa[4], fb[4];
#pragma unroll
      for (int ms = 0; ms < 4; ++ms) {
        int row = wm * 64 + ms * 16 + lr;
        int off = (kk * 64 + lg * 16) ^ ((row & 7) << 4);
        fa[ms] = *(const short8*)((const char*)lA + row * 128 + off);
      }
#pragma unroll
      for (int ns = 0; ns < 4; ++ns) {
        int row = wn * 64 + ns * 16 + lr;
        int off = (kk * 64 + lg * 16) ^ ((row & 7) << 4);
        fb[ns] = *(const short8*)((const char*)lB + row * 128 + off);
      }
#pragma unroll
      for (int ms = 0; ms < 4; ++ms)
#pragma unroll
        for (int ns = 0; ns < 4; ++ns)
          acc[ms][ns] = mfma16(fa[ms], fb[ns], acc[ms][ns]);
    }
    __syncthreads();
  }

  float* lC = (float*)smem;  // [128][66]
  for (int p = 0; p < 2; ++p) {
    if (p) __syncthreads();
    if (wn == p) {
#pragma unroll
      for (int ms = 0; ms < 4; ++ms)
#pragma unroll
        for (int ns = 0; ns < 4; ++ns) {
          int r = wm * 64 + ms * 16 + 4 * lg;
          int cc = ns * 16 + lr;
#pragma unroll
          for (int reg = 0; reg < 4; ++reg)
            lC[(r + reg) * 66 + cc] = acc[ms][ns][reg];
        }
    }
    __syncthreads();
    int r = tid >> 1, c0 = (tid & 1) * 32;
    int m = m0 + r;
    if (m < MP) {
      int bb = m / 462, tt = m % 462;
      int tok = idxk[bb * KEPTP + tt];
      int col = n0 + p * 64 + c0;
      const float* xs = x + ((size_t)(bb * 577) + tok) * 768 + col;
      float* dst = out + (size_t)m * 768 + col;
#pragma unroll
      for (int cc = 0; cc < 32; cc += 4) {
        f32x4 xv = *(const f32x4*)(xs + cc);
        f32x4 bv = *(const f32x4*)(pb + col + cc);
        f32x4 o;
#pragma unroll
        for (int j = 0; j < 4; ++j)
          o[j] = lC[r * 66 + c0 + cc + j] + bv[j] + xv[j];
        *(f32x4*)(dst + cc) = o;
      }
    }
  }
}

// ---------------- host launch ----------------
extern "C" void kernel_launch(void* const* d_in, const int* in_sizes, int n_in,
                              void* d_out, int out_size, void* d_ws, size_t ws_size,
                              hipStream_t stream) {
  const float* x  = (const float*)d_in[0];
  const float* qw = (const float*)d_in[1];
  const float* pw = (const float*)d_in[2];
  const float* pb = (const float*)d_in[3];
  (void)in_sizes; (void)n_in; (void)out_size; (void)ws_size;

  char* ws = (char*)d_ws;
  size_t off = 0;
  auto alloc = [&](size_t bytes) {
    void* p = ws + off;
    off += (bytes + 255) & ~(size_t)255;
    return p;
  };
  unsigned short* xh  = (unsigned short*)alloc((size_t)MQ * 768 * 2);
  unsigned short* xl  = (unsigned short*)alloc((size_t)MQ * 768 * 2);
  unsigned short* wh  = (unsigned short*)alloc((size_t)2304 * 768 * 2);
  unsigned short* wl  = (unsigned short*)alloc((size_t)2304 * 768 * 2);
  unsigned short* pwh = (unsigned short*)alloc((size_t)768 * 768 * 2);
  unsigned short* qhp = (unsigned short*)alloc((size_t)BH_ * NPAD * 64 * 2);
  unsigned short* qlp = (unsigned short*)alloc((size_t)BH_ * NPAD * 64 * 2);
  unsigned short* khp = (unsigned short*)alloc((size_t)BH_ * NPAD * 64 * 2);
  unsigned short* klp = (unsigned short*)alloc((size_t)BH_ * NPAD * 64 * 2);
  unsigned short* vtp = (unsigned short*)alloc((size_t)BH_ * NPAD * 64 * 2);
  unsigned short* Obf = (unsigned short*)alloc((size_t)BH_ * NPAD * 64 * 2);
  float* S0  = (float*)alloc((size_t)BH_ * NPAD * 4);
  float* Dg  = (float*)alloc((size_t)BH_ * NPAD * 4);
  int*   idxk = (int*)alloc((size_t)BB_ * KEPTP * 4);

  k_split_all<<<dim3(((NX4_ + NW4_ + NP4_) / 2 + 255) / 256), 256, 0, stream>>>(
      x, qw, pw, xh, xl, wh, wl, pwh);
  k_qkv<<<dim3(MT_ * NT_), 256, 0, stream>>>(xh, xl, wh, wl, qhp, qlp, khp, klp, vtp);
  k_attn1<<<dim3(1920), 256, 0, stream>>>(qhp, qlp, khp, klp, vtp, S0, Dg, Obf);
  k_select<<<dim3(32), 576, 0, stream>>>(Dg, S0, idxk);
  k_proj<<<dim3(696), 256, 0, stream>>>(Obf, pwh, pb, x, idxk, (float*)d_out);
}

// Round 13
// 376.041 us; speedup vs baseline: 2.7316x; 1.3047x over previous
//
#include <hip/hip_runtime.h>
#include <math.h>

// ---------------- problem constants ----------------
#define BB_   32
#define NN_   577
#define CC_   768
#define HH_   12
#define HD_   64
#define NPAD  640          // padded token dim (10 tiles of 64)
#define BH_   (BB_*HH_)    // 384
#define MQ    (BB_*NN_)    // 18464 rows of x
#define KEPT  462
#define KEPTP 464
#define MP    (BB_*KEPT)   // 14784
#define TOPK  461

#define MT_   145          // qkv m-tiles (128 rows)
#define NT_   18           // qkv n-tiles (128 cols)

using short8 = __attribute__((ext_vector_type(8))) short;
using f32x4  = __attribute__((ext_vector_type(4))) float;
using u16x4  = __attribute__((ext_vector_type(4))) unsigned short;
using u32x2  = __attribute__((ext_vector_type(2))) unsigned int;

using gp1_t = const __attribute__((address_space(1))) void*;
using sp3_t = __attribute__((address_space(3))) void*;

__device__ __forceinline__ unsigned short f2bf(float f) {
  unsigned int u = __float_as_uint(f);
  u += 0x7fffu + ((u >> 16) & 1u);
  return (unsigned short)(u >> 16);
}
__device__ __forceinline__ float bf2f(unsigned short h) {
  return __uint_as_float(((unsigned int)h) << 16);
}
__device__ __forceinline__ f32x4 mfma16(short8 a, short8 b, f32x4 c) {
  return __builtin_amdgcn_mfma_f32_16x16x32_bf16(a, b, c, 0, 0, 0);
}
__device__ __forceinline__ void gl_lds16(const void* g, void* l) {
  __builtin_amdgcn_global_load_lds((gp1_t)g, (sp3_t)l, 16, 0, 0);
}

#define SC_ 0.18033688011112042f   /* 0.125 * log2(e): exp2-domain logits */

// ---------------- K0: fused fp32 -> bf16 hi/lo splits (x, qkv_w, proj_w) ----
__device__ __forceinline__ void split4(const float* __restrict__ in, int i,
                                       unsigned short* __restrict__ hi,
                                       unsigned short* __restrict__ lo) {
  f32x4 f = *(const f32x4*)(in + (size_t)i * 4);
  u16x4 hv, lv;
#pragma unroll
  for (int j = 0; j < 4; ++j) {
    unsigned short h = f2bf(f[j]);
    hv[j] = h;
    lv[j] = f2bf(f[j] - bf2f(h));
  }
  *(u16x4*)(hi + (size_t)i * 4) = hv;
  if (lo) *(u16x4*)(lo + (size_t)i * 4) = lv;
}

#define NX4_ (MQ * 768 / 4)
#define NW4_ (2304 * 768 / 4)
#define NP4_ (768 * 768 / 4)

// all three 4-chunk counts are even, so a (2i, 2i+1) pair never straddles
__global__ __launch_bounds__(256) void k_split_all(
    const float* __restrict__ x, const float* __restrict__ qw,
    const float* __restrict__ pw,
    unsigned short* __restrict__ xh, unsigned short* __restrict__ xl,
    unsigned short* __restrict__ wh, unsigned short* __restrict__ wl,
    unsigned short* __restrict__ pwh) {
  int i2 = blockIdx.x * 256 + threadIdx.x;
#pragma unroll
  for (int s = 0; s < 2; ++s) {
    int i = 2 * i2 + s;
    if (i < NX4_) {
      split4(x, i, xh, xl);
    } else if (i < NX4_ + NW4_) {
      split4(qw, i - NX4_, wh, wl);
    } else if (i < NX4_ + NW4_ + NP4_) {
      split4(pw, i - NX4_ - NW4_, pwh, (unsigned short*)nullptr);
    }
  }
}

// ---------------- K1: QKV GEMM 128x128 tile, n-fastest + XCD swizzle --------
// (empirical best: BK=64, 2-barrier gload_lds for BOTH operands, 185 us.
//  Refuted alternatives: BK=32 stage-ahead (r7, bank conflicts 8.5x), counted
//  vmcnt (r9), launch_bounds(256,4) (r11, spills), B-direct-from-L2 (r12,
//  non-coalesced row reads serialize on L2 -> MfmaUtil 21%).)
__global__ __launch_bounds__(256, 2) void k_qkv(
    const unsigned short* __restrict__ xh, const unsigned short* __restrict__ xl,
    const unsigned short* __restrict__ wh, const unsigned short* __restrict__ wl,
    unsigned short* __restrict__ qh, unsigned short* __restrict__ ql,
    unsigned short* __restrict__ kh, unsigned short* __restrict__ kl,
    unsigned short* __restrict__ vt) {
  __shared__ char smem[65536];
  unsigned short* lAh = (unsigned short*)smem;
  unsigned short* lAl = (unsigned short*)(smem + 16384);
  unsigned short* lBh = (unsigned short*)(smem + 32768);
  unsigned short* lBl = (unsigned short*)(smem + 49152);

  const int tid = threadIdx.x;
  const int wave = tid >> 6, lane = tid & 63, lr = lane & 15, lg = lane >> 4;
  const int wm = wave >> 1, wn = wave & 1;

  const int nwg = MT_ * NT_;            // 2610
  const int qq = nwg >> 3, rr = nwg & 7; // 326, 2
  int orig = blockIdx.x;
  int xcd = orig & 7, pos = orig >> 3;
  int wgid = (xcd < rr ? xcd * (qq + 1) : rr * (qq + 1) + (xcd - rr) * qq) + pos;
  const int mt = wgid / NT_, nt = wgid - mt * NT_;
  const int m0 = mt * 128, n0 = nt * 128;
  const int which = n0 / 768;            // 0=q 1=k 2=v
  const bool three = (which < 2);

  f32x4 zf = {0.f, 0.f, 0.f, 0.f};
  f32x4 acc[4][4];
#pragma unroll
  for (int a = 0; a < 4; ++a)
#pragma unroll
    for (int bq = 0; bq < 4; ++bq) acc[a][bq] = zf;

  for (int ks = 0; ks < 12; ++ks) {
    const int k0 = ks * 64;
#pragma unroll
    for (int it = 0; it < 4; ++it) {
      int c = it * 256 + tid;
      int row = c >> 3, slot = c & 7;
      int grow = m0 + row; if (grow > MQ - 1) grow = MQ - 1;
      int gk = k0 + ((slot ^ (row & 7)) << 3);
      gl_lds16(xh + (size_t)grow * 768 + gk,
               (char*)lAh + (it * 256 + wave * 64) * 16);
      if (three)
        gl_lds16(xl + (size_t)grow * 768 + gk,
                 (char*)lAl + (it * 256 + wave * 64) * 16);
    }
#pragma unroll
    for (int it = 0; it < 4; ++it) {
      int c = it * 256 + tid;
      int row = c >> 3, slot = c & 7;
      int gn = n0 + row;
      int gk = k0 + ((slot ^ (row & 7)) << 3);
      gl_lds16(wh + (size_t)gn * 768 + gk,
               (char*)lBh + (it * 256 + wave * 64) * 16);
      if (three)
        gl_lds16(wl + (size_t)gn * 768 + gk,
                 (char*)lBl + (it * 256 + wave * 64) * 16);
    }
    __syncthreads();

#pragma unroll
    for (int kk = 0; kk < 2; ++kk) {
      short8 fa[4], fal[4], fb[4], fbl[4];
#pragma unroll
      for (int ms = 0; ms < 4; ++ms) {
        int row = wm * 64 + ms * 16 + lr;
        int off = (kk * 64 + lg * 16) ^ ((row & 7) << 4);
        fa[ms] = *(const short8*)((const char*)lAh + row * 128 + off);
        if (three) fal[ms] = *(const short8*)((const char*)lAl + row * 128 + off);
      }
#pragma unroll
      for (int ns = 0; ns < 4; ++ns) {
        int row = wn * 64 + ns * 16 + lr;
        int off = (kk * 64 + lg * 16) ^ ((row & 7) << 4);
        fb[ns] = *(const short8*)((const char*)lBh + row * 128 + off);
        if (three) fbl[ns] = *(const short8*)((const char*)lBl + row * 128 + off);
      }
#pragma unroll
      for (int ms = 0; ms < 4; ++ms)
#pragma unroll
        for (int ns = 0; ns < 4; ++ns) {
          acc[ms][ns] = mfma16(fa[ms], fb[ns], acc[ms][ns]);
          if (three) {
            acc[ms][ns] = mfma16(fa[ms], fbl[ns], acc[ms][ns]);
            acc[ms][ns] = mfma16(fal[ms], fb[ns], acc[ms][ns]);
          }
        }
    }
    __syncthreads();
  }

  if (which < 2) {
    float* lC = (float*)smem;  // [128][66]
    for (int p = 0; p < 2; ++p) {
      if (p) __syncthreads();
      if (wn == p) {
#pragma unroll
        for (int ms = 0; ms < 4; ++ms)
#pragma unroll
          for (int ns = 0; ns < 4; ++ns) {
            int r = wm * 64 + ms * 16 + 4 * lg;
            int cc = ns * 16 + lr;
#pragma unroll
            for (int reg = 0; reg < 4; ++reg)
              lC[(r + reg) * 66 + cc] = acc[ms][ns][reg];
          }
      }
      __syncthreads();
      const int h = ((n0 % 768) >> 6) + p;
      int r = tid >> 1, c0 = (tid & 1) * 32;
      int m = m0 + r;
      if (m < MQ) {
        int b = m / 577, n = m % 577;
        size_t base = ((size_t)(b * 12 + h) * NPAD + n) * 64 + c0;
        unsigned short* dh = (which == 0 ? qh : kh) + base;
        unsigned short* dl = (which == 0 ? ql : kl) + base;
#pragma unroll
        for (int cc = 0; cc < 32; cc += 4) {
          u16x4 hv, lv;
#pragma unroll
          for (int j = 0; j < 4; ++j) {
            float f = lC[r * 66 + c0 + cc + j];
            unsigned short hh = f2bf(f);
            hv[j] = hh;
            lv[j] = f2bf(f - bf2f(hh));
          }
          *(u16x4*)(dh + cc) = hv;
          *(u16x4*)(dl + cc) = lv;
        }
      }
    }
  } else {
    // V: direct fragment stores to transposed layout (B,H,64,NPAD)
    const int h0 = (n0 % 768) >> 6;
#pragma unroll
    for (int ms = 0; ms < 4; ++ms)
#pragma unroll
      for (int ns = 0; ns < 4; ++ns) {
        int m = m0 + wm * 64 + ms * 16 + 4 * lg;
        int c = wn * 64 + ns * 16 + lr;
        int h = h0 + (c >> 6), d = c & 63;
        int b = m / 577, n = m - b * 577;
        if (m + 3 < MQ && n + 3 < 577) {
          u16x4 pv;
#pragma unroll
          for (int reg = 0; reg < 4; ++reg) pv[reg] = f2bf(acc[ms][ns][reg]);
          *(u16x4*)(vt + ((size_t)(b * 12 + h) * 64 + d) * NPAD + n) = pv;
        } else {
#pragma unroll
          for (int reg = 0; reg < 4; ++reg) {
            int mm = m + reg;
            if (mm < MQ) {
              int bb = mm / 577, nn = mm - bb * 577;
              vt[((size_t)(bb * 12 + h) * 64 + d) * NPAD + nn] = f2bf(acc[ms][ns][reg]);
            }
          }
        }
      }
  }
}

// ---------------- K2: fused 3-term QK^T + rowsum + PV + normalize + diag ----
// linear grid 1920, block 256 (4 waves). Wave w owns i-rows [i0+32w, +32)
// (two 16-row groups); iterates ALL j in 32-wide chunks; K/V staged in dbuf
// LDS (one barrier/chunk); P relayout via wave-private LDS (no barriers).
__global__ __launch_bounds__(256) void k_attn1(
    const unsigned short* __restrict__ qh, const unsigned short* __restrict__ ql,
    const unsigned short* __restrict__ kh, const unsigned short* __restrict__ kl,
    const unsigned short* __restrict__ vt, float* __restrict__ S0,
    float* __restrict__ Dg, unsigned short* __restrict__ Ob) {
  __shared__ char smem[45056];
  char* lK = smem;            // 2 bufs x (hi[32][128B] | lo[32][128B]) = 16384
  char* lV = smem + 16384;    // 2 bufs x V^T[64][64B] = 8192
  char* lP = smem + 24576;    // 4 waves x 2 iu x 2 pb x [16][80B] = 20480

  int wgid = (blockIdx.x & 7) * 240 + (blockIdx.x >> 3);  // 1920 = 8*240
  const int bh = wgid / 5;
  const int i0 = (wgid - bh * 5) * 128;
  const int tid = threadIdx.x, w = tid >> 6, lane = tid & 63;
  const int lr = lane & 15, lg = lane >> 4;
  const size_t qb = (size_t)bh * NPAD * 64;

  // staging geometry
  const int krow = tid >> 3, kslot = tid & 7;   // K: 32 rows x 8 x 16B
  const int vrow = tid >> 2, vslot = tid & 3;   // V: 64 rows x 4 x 16B
  const size_t ksrc = (size_t)krow * 64 + ((kslot ^ (krow & 7)) << 3);
  const size_t vsrc = ((size_t)bh * 64 + vrow) * NPAD + ((vslot ^ (vrow & 3)) << 3);

  // Q fragments (B-operand): row = i0 + 32w + 16*iu + lr, k = kk*32 + lg*8
  short8 qf[2][2], qfl[2][2];
#pragma unroll
  for (int iu = 0; iu < 2; ++iu) {
    const size_t qrow = qb + (size_t)(i0 + w * 32 + iu * 16 + lr) * 64;
#pragma unroll
    for (int kk = 0; kk < 2; ++kk) {
      qf[iu][kk]  = *(const short8*)(qh + qrow + kk * 32 + lg * 8);
      qfl[iu][kk] = *(const short8*)(ql + qrow + kk * 32 + lg * 8);
    }
  }
  f32x4 zf = {0.f, 0.f, 0.f, 0.f};
  f32x4 oacc[2][4];
#pragma unroll
  for (int iu = 0; iu < 2; ++iu)
#pragma unroll
    for (int ds = 0; ds < 4; ++ds) oacc[iu][ds] = zf;
  float s0[2] = {0.0f, 0.0f};

  // prologue: stage chunk 0 into buf 0
  gl_lds16(kh + qb + ksrc, lK + tid * 16);
  gl_lds16(kl + qb + ksrc, lK + 4096 + tid * 16);
  gl_lds16(vt + vsrc, lV + tid * 16);
  __syncthreads();

  int buf = 0, pb = 0;
  char* lPw = lP + w * 5120;
  for (int jp = 0; jp < 19; ++jp) {
    if (jp < 18) {  // issue next-chunk stage; drains at this chunk's barrier
      int jn = (jp + 1) * 32;
      gl_lds16(kh + qb + (size_t)jn * 64 + ksrc, lK + (buf ^ 1) * 8192 + tid * 16);
      gl_lds16(kl + qb + (size_t)jn * 64 + ksrc, lK + (buf ^ 1) * 8192 + 4096 + tid * 16);
      gl_lds16(vt + vsrc + jn, lV + (buf ^ 1) * 4096 + tid * 16);
    }
#pragma unroll
    for (int t = 0; t < 2; ++t) {
      const int jloc = t * 16 + lr;
      short8 kfh[2], kfl2[2];
#pragma unroll
      for (int kk = 0; kk < 2; ++kk) {
        int off = (kk * 64 + lg * 16) ^ ((jloc & 7) << 4);
        kfh[kk]  = *(const short8*)(lK + buf * 8192 + jloc * 128 + off);
        kfl2[kk] = *(const short8*)(lK + buf * 8192 + 4096 + jloc * 128 + off);
      }
      int jbase = jp * 32 + t * 16 + 4 * lg;
#pragma unroll
      for (int iu = 0; iu < 2; ++iu) {
        f32x4 c = zf;
#pragma unroll
        for (int kk = 0; kk < 2; ++kk) {
          c = mfma16(kfh[kk], qfl[iu][kk], c);
          c = mfma16(kfl2[kk], qf[iu][kk], c);
          c = mfma16(kfh[kk], qf[iu][kk], c);
        }
        // c: [col=i=lr][row=j = t*16 + 4lg+reg]
        float p0 = (jbase + 0 < 577) ? exp2f(c[0] * SC_) : 0.0f;
        float p1 = (jbase + 1 < 577) ? exp2f(c[1] * SC_) : 0.0f;
        float p2 = (jbase + 2 < 577) ? exp2f(c[2] * SC_) : 0.0f;
        float p3 = (jbase + 3 < 577) ? exp2f(c[3] * SC_) : 0.0f;
        s0[iu] += (p0 + p1) + (p2 + p3);
        u32x2 wv;
        wv[0] = (unsigned)f2bf(p0) | ((unsigned)f2bf(p1) << 16);
        wv[1] = (unsigned)f2bf(p2) | ((unsigned)f2bf(p3) << 16);
        *(u32x2*)(lPw + iu * 2560 + pb * 1280 + lr * 80 + t * 32 + lg * 8) = wv;
      }
    }
    asm volatile("" ::: "memory");
    // PV: A = P[i=lr][j 0..31], B = V^T[d][j 0..31]
#pragma unroll
    for (int iu = 0; iu < 2; ++iu) {
      short8 pa = *(const short8*)(lPw + iu * 2560 + pb * 1280 + lr * 80 + lg * 16);
#pragma unroll
      for (int ds = 0; ds < 4; ++ds) {
        int r = ds * 16 + lr;
        int off = (lg * 16) ^ ((r & 3) << 4);
        short8 vf = *(const short8*)(lV + buf * 4096 + r * 64 + off);
        oacc[iu][ds] = mfma16(pa, vf, oacc[iu][ds]);
      }
    }
    asm volatile("" ::: "memory");
    pb ^= 1;
    __syncthreads();   // drains staged loads; releases buf for next overwrite
    buf ^= 1;
  }

  // wave-private epilogue: rowsum reduce, normalize, store
#pragma unroll
  for (int iu = 0; iu < 2; ++iu) {
    float s = s0[iu];
    s += __shfl_xor(s, 16);
    s += __shfl_xor(s, 32);          // lane holds S0[i = lr]
    const int iw = i0 + w * 32 + iu * 16;
    if (lg == 0) S0[(size_t)bh * NPAD + iw + lr] = s;
    float rs[4];
#pragma unroll
    for (int reg = 0; reg < 4; ++reg) rs[reg] = 1.0f / __shfl(s, 4 * lg + reg);
#pragma unroll
    for (int ds = 0; ds < 4; ++ds)
#pragma unroll
      for (int reg = 0; reg < 4; ++reg)
        Ob[((size_t)bh * NPAD + iw + 4 * lg + reg) * 64 + ds * 16 + lr] =
            f2bf(oacc[iu][ds][reg] * rs[reg]);
  }

  // exact fp32 diag logits from hi+lo (rows i0..i0+127; L2-hot)
#pragma unroll
  for (int rr = 0; rr < 2; ++rr) {
    const int row = i0 + rr * 64 + (tid >> 2);
    const int c = tid & 3;
    const size_t base = qb + (size_t)row * 64 + c * 16;
    short8 a0 = *(const short8*)(qh + base), a1 = *(const short8*)(qh + base + 8);
    short8 b0 = *(const short8*)(ql + base), b1 = *(const short8*)(ql + base + 8);
    short8 c0 = *(const short8*)(kh + base), c1 = *(const short8*)(kh + base + 8);
    short8 d0 = *(const short8*)(kl + base), d1 = *(const short8*)(kl + base + 8);
    float acc = 0.0f;
#pragma unroll
    for (int j = 0; j < 8; ++j) {
      float qv = bf2f((unsigned short)a0[j]) + bf2f((unsigned short)b0[j]);
      float kv = bf2f((unsigned short)c0[j]) + bf2f((unsigned short)d0[j]);
      acc += qv * kv;
      float qv1 = bf2f((unsigned short)a1[j]) + bf2f((unsigned short)b1[j]);
      float kv1 = bf2f((unsigned short)c1[j]) + bf2f((unsigned short)d1[j]);
      acc += qv1 * kv1;
    }
    acc += __shfl_xor(acc, 1, 4);
    acc += __shfl_xor(acc, 2, 4);
    if (c == 0) Dg[(size_t)bh * NPAD + row] = acc * SC_;
  }
}

// ---------------- K4: head-mean diag + stable top-461 via pairwise rank -----
__global__ __launch_bounds__(576) void k_select(const float* __restrict__ Dg,
                                                const float* __restrict__ S0,
                                                int* __restrict__ idxk) {
  __shared__ float kbuf[576];
  __shared__ int kflag[576];
  int b = blockIdx.x, t = threadIdx.x;
  if (t < 576) {
    float a = 0.0f;
#pragma unroll
    for (int h = 0; h < 12; ++h) {
      size_t o = (size_t)(b * 12 + h) * NPAD + t + 1;
      a += exp2f(Dg[o]) / S0[o];
    }
    kbuf[t] = a;  // ranking is scale-invariant: skip /12
  }
  __syncthreads();
  if (t < 576) {
    float kt = kbuf[t];
    int cnt = 0;
    for (int j = 0; j < 576; ++j) {
      float kj = kbuf[j];
      cnt += (kj > kt || (kj == kt && j < t)) ? 1 : 0;
    }
    kflag[t] = (cnt < TOPK) ? 1 : 0;
  }
  __syncthreads();
  if (t < 576 && kflag[t]) {
    int pos = 1;  // CLS occupies 0
    for (int j = 0; j < t; ++j) pos += kflag[j];
    idxk[b * KEPTP + pos] = t + 1;
  }
  if (t == 0) {
    idxk[b * KEPTP + 0] = 0;
    idxk[b * KEPTP + 462] = 0;
    idxk[b * KEPTP + 463] = 0;
  }
}

// ---------------- K6: proj GEMM 128x128 + bias + residual gather ------------
// A-panel gathered from Ob via idxk (h = ks). linear grid 696, n-fastest.
__global__ __launch_bounds__(256) void k_proj(
    const unsigned short* __restrict__ Ob, const unsigned short* __restrict__ pwh,
    const float* __restrict__ pb, const float* __restrict__ x,
    const int* __restrict__ idxk, float* __restrict__ out) {
  __shared__ char smem[33792];
  unsigned short* lA = (unsigned short*)smem;
  unsigned short* lB = (unsigned short*)(smem + 16384);
  const int tid = threadIdx.x;
  const int wave = tid >> 6, lane = tid & 63, lr = lane & 15, lg = lane >> 4;
  const int wm = wave >> 1, wn = wave & 1;
  int wgid = (blockIdx.x & 7) * 87 + (blockIdx.x >> 3);  // 696 = 8*87
  const int mt = wgid / 6, nt = wgid - mt * 6;
  const int m0 = mt * 128, n0 = nt * 128;

  // per-thread token/batch for the 4 A-chunks (fixed across K-steps)
  int tokr[4], bbr[4], offr8[4];
#pragma unroll
  for (int it = 0; it < 4; ++it) {
    int c = it * 256 + tid;
    int row = c >> 3, slot = c & 7;
    int m = m0 + row; if (m > MP - 1) m = MP - 1;
    int bb = m / 462, tt = m - bb * 462;
    tokr[it] = idxk[bb * KEPTP + tt];
    bbr[it] = bb;
    offr8[it] = (slot ^ (row & 7)) << 3;
  }

  f32x4 zf = {0.f, 0.f, 0.f, 0.f};
  f32x4 acc[4][4];
#pragma unroll
  for (int a = 0; a < 4; ++a)
#pragma unroll
    for (int bq = 0; bq < 4; ++bq) acc[a][bq] = zf;

  for (int ks = 0; ks < 12; ++ks) {
    int k0 = ks * 64;
#pragma unroll
    for (int it = 0; it < 4; ++it) {
      gl_lds16(Ob + ((size_t)(bbr[it] * 12 + ks) * NPAD + tokr[it]) * 64 + offr8[it],
               (char*)lA + (it * 256 + wave * 64) * 16);
    }
#pragma unroll
    for (int it = 0; it < 4; ++it) {
      int c = it * 256 + tid;
      int row = c >> 3, slot = c & 7;
      int gk = k0 + ((slot ^ (row & 7)) << 3);
      gl_lds16(pwh + (size_t)(n0 + row) * 768 + gk,
               (char*)lB + (it * 256 + wave * 64) * 16);
    }
    __syncthreads();
#pragma unroll
    for (int kk = 0; kk < 2; ++kk) {
      short8 fa[4], fb[4];
#pragma unroll
      for (int ms = 0; ms < 4; ++ms) {
        int row = wm * 64 + ms * 16 + lr;
        int off = (kk * 64 + lg * 16) ^ ((row & 7) << 4);
        fa[ms] = *(const short8*)((const char*)lA + row * 128 + off);
      }
#pragma unroll
      for (int ns = 0; ns < 4; ++ns) {
        int row = wn * 64 + ns * 16 + lr;
        int off = (kk * 64 + lg * 16) ^ ((row & 7) << 4);
        fb[ns] = *(const short8*)((const char*)lB + row * 128 + off);
      }
#pragma unroll
      for (int ms = 0; ms < 4; ++ms)
#pragma unroll
        for (int ns = 0; ns < 4; ++ns)
          acc[ms][ns] = mfma16(fa[ms], fb[ns], acc[ms][ns]);
    }
    __syncthreads();
  }

  float* lC = (float*)smem;  // [128][66]
  for (int p = 0; p < 2; ++p) {
    if (p) __syncthreads();
    if (wn == p) {
#pragma unroll
      for (int ms = 0; ms < 4; ++ms)
#pragma unroll
        for (int ns = 0; ns < 4; ++ns) {
          int r = wm * 64 + ms * 16 + 4 * lg;
          int cc = ns * 16 + lr;
#pragma unroll
          for (int reg = 0; reg < 4; ++reg)
            lC[(r + reg) * 66 + cc] = acc[ms][ns][reg];
        }
    }
    __syncthreads();
    int r = tid >> 1, c0 = (tid & 1) * 32;
    int m = m0 + r;
    if (m < MP) {
      int bb = m / 462, tt = m % 462;
      int tok = idxk[bb * KEPTP + tt];
      int col = n0 + p * 64 + c0;
      const float* xs = x + ((size_t)(bb * 577) + tok) * 768 + col;
      float* dst = out + (size_t)m * 768 + col;
#pragma unroll
      for (int cc = 0; cc < 32; cc += 4) {
        f32x4 xv = *(const f32x4*)(xs + cc);
        f32x4 bv = *(const f32x4*)(pb + col + cc);
        f32x4 o;
#pragma unroll
        for (int j = 0; j < 4; ++j)
          o[j] = lC[r * 66 + c0 + cc + j] + bv[j] + xv[j];
        *(f32x4*)(dst + cc) = o;
      }
    }
  }
}

// ---------------- host launch ----------------
extern "C" void kernel_launch(void* const* d_in, const int* in_sizes, int n_in,
                              void* d_out, int out_size, void* d_ws, size_t ws_size,
                              hipStream_t stream) {
  const float* x  = (const float*)d_in[0];
  const float* qw = (const float*)d_in[1];
  const float* pw = (const float*)d_in[2];
  const float* pb = (const float*)d_in[3];
  (void)in_sizes; (void)n_in; (void)out_size; (void)ws_size;

  char* ws = (char*)d_ws;
  size_t off = 0;
  auto alloc = [&](size_t bytes) {
    void* p = ws + off;
    off += (bytes + 255) & ~(size_t)255;
    return p;
  };
  unsigned short* xh  = (unsigned short*)alloc((size_t)MQ * 768 * 2);
  unsigned short* xl  = (unsigned short*)alloc((size_t)MQ * 768 * 2);
  unsigned short* wh  = (unsigned short*)alloc((size_t)2304 * 768 * 2);
  unsigned short* wl  = (unsigned short*)alloc((size_t)2304 * 768 * 2);
  unsigned short* pwh = (unsigned short*)alloc((size_t)768 * 768 * 2);
  unsigned short* qhp = (unsigned short*)alloc((size_t)BH_ * NPAD * 64 * 2);
  unsigned short* qlp = (unsigned short*)alloc((size_t)BH_ * NPAD * 64 * 2);
  unsigned short* khp = (unsigned short*)alloc((size_t)BH_ * NPAD * 64 * 2);
  unsigned short* klp = (unsigned short*)alloc((size_t)BH_ * NPAD * 64 * 2);
  unsigned short* vtp = (unsigned short*)alloc((size_t)BH_ * NPAD * 64 * 2);
  unsigned short* Obf = (unsigned short*)alloc((size_t)BH_ * NPAD * 64 * 2);
  float* S0  = (float*)alloc((size_t)BH_ * NPAD * 4);
  float* Dg  = (float*)alloc((size_t)BH_ * NPAD * 4);
  int*   idxk = (int*)alloc((size_t)BB_ * KEPTP * 4);

  k_split_all<<<dim3(((NX4_ + NW4_ + NP4_) / 2 + 255) / 256), 256, 0, stream>>>(
      x, qw, pw, xh, xl, wh, wl, pwh);
  k_qkv<<<dim3(MT_ * NT_), 256, 0, stream>>>(xh, xl, wh, wl, qhp, qlp, khp, klp, vtp);
  k_attn1<<<dim3(1920), 256, 0, stream>>>(qhp, qlp, khp, klp, vtp, S0, Dg, Obf);
  k_select<<<dim3(32), 576, 0, stream>>>(Dg, S0, idxk);
  k_proj<<<dim3(696), 256, 0, stream>>>(Obf, pwh, pb, x, idxk, (float*)d_out);
}